// Round 1
// baseline (276.371 us; speedup 1.0000x reference)
//
#include <hip/hip_runtime.h>
#include <hip/hip_cooperative_groups.h>
#include <stdint.h>

namespace cg = cooperative_groups;

#define NROWS 32768
#define DDIM  512
#define FDIM  64

typedef __attribute__((ext_vector_type(4))) float f32x4;
typedef __attribute__((ext_vector_type(8))) short bf16x8;

// RNE fp32->bf16 (no NaN path: inputs are finite randn products)
static __device__ __forceinline__ unsigned short f2bf_rne(float x) {
    unsigned u = __builtin_bit_cast(unsigned, x);
    u += 0x7fffu + ((u >> 16) & 1u);
    return (unsigned short)(u >> 16);
}
// pack two fp32 -> bf16x2 in one u32 (compiler folds the merge to v_perm)
static __device__ __forceinline__ unsigned pack2_bf16(float a, float b) {
    unsigned ua = __builtin_bit_cast(unsigned, a);
    unsigned ub = __builtin_bit_cast(unsigned, b);
    ua += 0x7fffu + ((ua >> 16) & 1u);
    ub += 0x7fffu + ((ub >> 16) & 1u);
    return (ua >> 16) | (ub & 0xffff0000u);
}

static __device__ __forceinline__ void async_copy16(const void* g, void* l) {
    __builtin_amdgcn_global_load_lds(
        (const __attribute__((address_space(1))) unsigned int*)g,
        (__attribute__((address_space(3))) unsigned int*)l,
        16, 0, 0);
}

static __device__ __forceinline__ float dot8(const float4 a0, const float4 a1,
                                             const float4 x0, const float4 x1v) {
    return a0.x * x0.x + a0.y * x0.y + a0.z * x0.z + a0.w * x0.w
         + a1.x * x1v.x + a1.y * x1v.y + a1.z * x1v.z + a1.w * x1v.w;
}

// ---------------------------------------------------------------------------
// Fused cooperative kernel: 512 blocks x 256 thr, exactly 2 blocks/CU.
// Phase 1: grid-strided reduction of W/V2 -> M (bf16, frag order) + c.
// grid.sync()
// Phase 2: fm = x1 @ M^T + c ; denom = max(sum|fm|,eps) ; out = relu(fm/denom)@U
// ---------------------------------------------------------------------------
__global__ __launch_bounds__(256, 2) void fused_kernel(
    const float* __restrict__ x1,
    const float* __restrict__ x2,
    const float* __restrict__ V,
    const float* __restrict__ W,
    const float* __restrict__ b,
    const float* __restrict__ U,
    unsigned short* __restrict__ Mg,   // ws: 64*512 bf16 (frag order)
    float* __restrict__ cg_,           // ws: [64] fp32
    float* __restrict__ out)           // [32768]
{
    __shared__ uint4 Mlds[4096];   // 64 KB

    int tid  = threadIdx.x;
    int wave = tid >> 6;
    int lane = tid & 63;
    int gw   = blockIdx.x * 4 + wave;          // 0..2047

    // ---------------- Phase 1: build M (16 rows/wave, strided by 2048) -----
    const float4* xx = (const float4*)x2;
    float4 x0  = xx[lane];                     // x2 held in regs, reused 17x
    float4 x1v = xx[lane + 64];

    float4 ca[4][2], na[4][2];

    #pragma unroll
    for (int i = 0; i < 4; ++i) {
        int r = gw + i * 2048;
        const float4* src = (const float4*)(W + (size_t)r * DDIM);
        ca[i][0] = src[lane];
        ca[i][1] = src[lane + 64];
    }

    #pragma unroll
    for (int k = 0; k < 4; ++k) {
        if (k < 3) {
            #pragma unroll
            for (int i = 0; i < 4; ++i) {
                int r = gw + ((k + 1) * 4 + i) * 2048;
                const float4* src = (const float4*)(W + (size_t)r * DDIM);
                na[i][0] = src[lane];
                na[i][1] = src[lane + 64];
            }
        }
        #pragma unroll
        for (int i = 0; i < 4; ++i) {
            int r = gw + (k * 4 + i) * 2048;
            float s = dot8(ca[i][0], ca[i][1], x0, x1v);
            #pragma unroll
            for (int m = 32; m >= 1; m >>= 1) s += __shfl_xor(s, m);
            if (lane == 0) {
                int f = r >> 9, d = r & 511;
                float mval = s + V[(size_t)f * (2 * DDIM) + d];
                // MFMA B-frag order so phase-2 staging is a linear copy
                int t  = f >> 4, fl2 = f & 15;
                int ks = d >> 5, sub = (d >> 3) & 3, j = d & 7;
                int fragidx = (((ks * 4 + t) * 64 + sub * 16 + fl2) << 3) + j;
                Mg[fragidx] = f2bf_rne(mval);
            }
        }
        if (k < 3) {
            #pragma unroll
            for (int i = 0; i < 4; ++i) { ca[i][0] = na[i][0]; ca[i][1] = na[i][1]; }
        }
    }

    // c rows (waves 0..63): c[f] = b[f] + dot(V[f][512:], x2)
    if (gw < FDIM) {
        const float4* src = (const float4*)(V + (size_t)gw * (2 * DDIM) + DDIM);
        float4 a0 = src[lane], a1 = src[lane + 64];
        float s = dot8(a0, a1, x0, x1v);
        #pragma unroll
        for (int m = 32; m >= 1; m >>= 1) s += __shfl_xor(s, m);
        if (lane == 0) cg_[gw] = s + b[gw];
    }

    __threadfence();               // release M/c device-wide
    cg::this_grid().sync();
    __threadfence();               // acquire

    // ---------------- Phase 2: GEMV + L1-normalize + relu + @U -------------
    const uint4* Msrc = (const uint4*)Mg;
    #pragma unroll
    for (int it = 0; it < 16; ++it) {
        int base = it * 256 + wave * 64;
        async_copy16(Msrc + base + lane, &Mlds[base]);
    }
    __syncthreads();   // drains vmcnt(0)

    int q  = lane >> 4;     // quad
    int fl = lane & 15;

    int row0 = blockIdx.x * 64 + wave * 16;
    const float* arow = x1 + (size_t)(row0 + fl) * DDIM + q * 8;

    const bf16x8* Mf = (const bf16x8*)Mlds;

    f32x4 acc0 = {0.f,0.f,0.f,0.f}, acc1 = {0.f,0.f,0.f,0.f};
    f32x4 acc2 = {0.f,0.f,0.f,0.f}, acc3 = {0.f,0.f,0.f,0.f};

    #pragma unroll 4
    for (int ks = 0; ks < 16; ++ks) {
        float4 av0 = *(const float4*)(arow + ks * 32);
        float4 av1 = *(const float4*)(arow + ks * 32 + 4);

        union { bf16x8 v; unsigned u32[4]; } af;
        af.u32[0] = pack2_bf16(av0.x, av0.y);
        af.u32[1] = pack2_bf16(av0.z, av0.w);
        af.u32[2] = pack2_bf16(av1.x, av1.y);
        af.u32[3] = pack2_bf16(av1.z, av1.w);

        bf16x8 b0 = Mf[(ks * 4 + 0) * 64 + lane];
        bf16x8 b1 = Mf[(ks * 4 + 1) * 64 + lane];
        bf16x8 b2 = Mf[(ks * 4 + 2) * 64 + lane];
        bf16x8 b3 = Mf[(ks * 4 + 3) * 64 + lane];

        acc0 = __builtin_amdgcn_mfma_f32_16x16x32_bf16(af.v, b0, acc0, 0, 0, 0);
        acc1 = __builtin_amdgcn_mfma_f32_16x16x32_bf16(af.v, b1, acc1, 0, 0, 0);
        acc2 = __builtin_amdgcn_mfma_f32_16x16x32_bf16(af.v, b2, acc2, 0, 0, 0);
        acc3 = __builtin_amdgcn_mfma_f32_16x16x32_bf16(af.v, b3, acc3, 0, 0, 0);
    }

    // Epilogue. C/D layout: col(f_local)=lane&15, row=q*4+reg.
    float cf0 = cg_[fl], cf1 = cg_[16 + fl], cf2 = cg_[32 + fl], cf3 = cg_[48 + fl];
    float uf0 = U[fl],   uf1 = U[16 + fl],  uf2 = U[32 + fl],  uf3 = U[48 + fl];

    #pragma unroll
    for (int r = 0; r < 4; ++r) {
        float f0 = acc0[r] + cf0;
        float f1 = acc1[r] + cf1;
        float f2 = acc2[r] + cf2;
        float f3 = acc3[r] + cf3;

        float s = fabsf(f0) + fabsf(f1) + fabsf(f2) + fabsf(f3);
        s += __shfl_xor(s, 1); s += __shfl_xor(s, 2);
        s += __shfl_xor(s, 4); s += __shfl_xor(s, 8);
        float denom = fmaxf(s, 1e-12f);

        float o = fmaxf(f0, 0.f) * uf0 + fmaxf(f1, 0.f) * uf1
                + fmaxf(f2, 0.f) * uf2 + fmaxf(f3, 0.f) * uf3;
        o += __shfl_xor(o, 1); o += __shfl_xor(o, 2);
        o += __shfl_xor(o, 4); o += __shfl_xor(o, 8);

        if (fl == 0) {
            out[row0 + q * 4 + r] = o / denom;
        }
    }
}

// ---------------------------------------------------------------------------
// Fallback path (previous best): two kernels, in case cooperative launch
// is rejected by graph capture.
// ---------------------------------------------------------------------------
__global__ __launch_bounds__(256) void prep_kernel(
    const float* __restrict__ x2,
    const float* __restrict__ V,
    const float* __restrict__ W,
    const float* __restrict__ b,
    unsigned short* __restrict__ Mout,
    float* __restrict__ cout)
{
    int wave = (blockIdx.x * 256 + threadIdx.x) >> 6;
    int lane = threadIdx.x & 63;

    const float4* src;
    if (wave < FDIM * DDIM) {
        src = (const float4*)(W + (size_t)wave * DDIM);
    } else {
        int f = wave - FDIM * DDIM;
        src = (const float4*)(V + (size_t)f * (2 * DDIM) + DDIM);
    }
    const float4* xx = (const float4*)x2;

    float4 a0 = src[lane];
    float4 a1 = src[lane + 64];
    float4 x0 = xx[lane];
    float4 x1v = xx[lane + 64];

    float s = dot8(a0, a1, x0, x1v);

    #pragma unroll
    for (int m = 32; m >= 1; m >>= 1) s += __shfl_xor(s, m);

    if (lane == 0) {
        if (wave < FDIM * DDIM) {
            int f = wave >> 9, d = wave & 511;
            float mval = s + V[(size_t)f * (2 * DDIM) + d];
            int t  = f >> 4, fl = f & 15;
            int ks = d >> 5, sub = (d >> 3) & 3, j = d & 7;
            int fragidx = (((ks * 4 + t) * 64 + sub * 16 + fl) << 3) + j;
            Mout[fragidx] = f2bf_rne(mval);
        } else {
            int f = wave - FDIM * DDIM;
            cout[f] = s + b[f];
        }
    }
}

__global__ __launch_bounds__(256, 2) void main_kernel(
    const float* __restrict__ x1,
    const unsigned short* __restrict__ Mg,
    const float* __restrict__ cg_,
    const float* __restrict__ U,
    float* __restrict__ out)
{
    __shared__ uint4 Mlds[4096];   // 64 KB

    int tid  = threadIdx.x;
    int wave = tid >> 6;
    int lane = tid & 63;

    const uint4* Msrc = (const uint4*)Mg;
    #pragma unroll
    for (int it = 0; it < 16; ++it) {
        int base = it * 256 + wave * 64;
        async_copy16(Msrc + base + lane, &Mlds[base]);
    }
    __syncthreads();

    int q  = lane >> 4;
    int fl = lane & 15;

    int row0 = blockIdx.x * 64 + wave * 16;
    const float* arow = x1 + (size_t)(row0 + fl) * DDIM + q * 8;

    const bf16x8* Mf = (const bf16x8*)Mlds;

    f32x4 acc0 = {0.f,0.f,0.f,0.f}, acc1 = {0.f,0.f,0.f,0.f};
    f32x4 acc2 = {0.f,0.f,0.f,0.f}, acc3 = {0.f,0.f,0.f,0.f};

    #pragma unroll 4
    for (int ks = 0; ks < 16; ++ks) {
        float4 av0 = *(const float4*)(arow + ks * 32);
        float4 av1 = *(const float4*)(arow + ks * 32 + 4);

        union { bf16x8 v; unsigned u32[4]; } af;
        af.u32[0] = pack2_bf16(av0.x, av0.y);
        af.u32[1] = pack2_bf16(av0.z, av0.w);
        af.u32[2] = pack2_bf16(av1.x, av1.y);
        af.u32[3] = pack2_bf16(av1.z, av1.w);

        bf16x8 b0 = Mf[(ks * 4 + 0) * 64 + lane];
        bf16x8 b1 = Mf[(ks * 4 + 1) * 64 + lane];
        bf16x8 b2 = Mf[(ks * 4 + 2) * 64 + lane];
        bf16x8 b3 = Mf[(ks * 4 + 3) * 64 + lane];

        acc0 = __builtin_amdgcn_mfma_f32_16x16x32_bf16(af.v, b0, acc0, 0, 0, 0);
        acc1 = __builtin_amdgcn_mfma_f32_16x16x32_bf16(af.v, b1, acc1, 0, 0, 0);
        acc2 = __builtin_amdgcn_mfma_f32_16x16x32_bf16(af.v, b2, acc2, 0, 0, 0);
        acc3 = __builtin_amdgcn_mfma_f32_16x16x32_bf16(af.v, b3, acc3, 0, 0, 0);
    }

    float cf0 = cg_[fl], cf1 = cg_[16 + fl], cf2 = cg_[32 + fl], cf3 = cg_[48 + fl];
    float uf0 = U[fl],   uf1 = U[16 + fl],  uf2 = U[32 + fl],  uf3 = U[48 + fl];

    #pragma unroll
    for (int r = 0; r < 4; ++r) {
        float f0 = acc0[r] + cf0;
        float f1 = acc1[r] + cf1;
        float f2 = acc2[r] + cf2;
        float f3 = acc3[r] + cf3;

        float s = fabsf(f0) + fabsf(f1) + fabsf(f2) + fabsf(f3);
        s += __shfl_xor(s, 1); s += __shfl_xor(s, 2);
        s += __shfl_xor(s, 4); s += __shfl_xor(s, 8);
        float denom = fmaxf(s, 1e-12f);

        float o = fmaxf(f0, 0.f) * uf0 + fmaxf(f1, 0.f) * uf1
                + fmaxf(f2, 0.f) * uf2 + fmaxf(f3, 0.f) * uf3;
        o += __shfl_xor(o, 1); o += __shfl_xor(o, 2);
        o += __shfl_xor(o, 4); o += __shfl_xor(o, 8);

        if (fl == 0) {
            out[row0 + q * 4 + r] = o / denom;
        }
    }
}

extern "C" void kernel_launch(void* const* d_in, const int* in_sizes, int n_in,
                              void* d_out, int out_size, void* d_ws, size_t ws_size,
                              hipStream_t stream) {
    const float* x1 = (const float*)d_in[0];
    const float* x2 = (const float*)d_in[1];
    const float* V  = (const float*)d_in[2];
    const float* W  = (const float*)d_in[3];
    const float* b  = (const float*)d_in[4];
    const float* U  = (const float*)d_in[5];
    float* outp = (float*)d_out;

    unsigned short* M = (unsigned short*)d_ws;                   // 64*512 bf16 = 64 KB (frag order)
    float* c          = (float*)((char*)d_ws + FDIM * DDIM * 2); // 64 fp32

    void* kargs[] = { (void*)&x1, (void*)&x2, (void*)&V, (void*)&W, (void*)&b,
                      (void*)&U,  (void*)&M,  (void*)&c, (void*)&outp };
    hipError_t e = hipLaunchCooperativeKernel((const void*)fused_kernel,
                                              dim3(512), dim3(256), kargs, 0, stream);
    if (e != hipSuccess) {
        // fallback: previous-best two-kernel path
        prep_kernel<<<8208, 256, 0, stream>>>(x2, V, W, b, M, c);
        main_kernel<<<512, 256, 0, stream>>>(x1, M, c, U, outp);
    }
}

// Round 2
// 153.226 us; speedup vs baseline: 1.8037x; 1.8037x over previous
//
#include <hip/hip_runtime.h>
#include <stdint.h>

#define NROWS 32768
#define DDIM  512
#define FDIM  64

typedef __attribute__((ext_vector_type(4))) float f32x4;
typedef __attribute__((ext_vector_type(8))) short bf16x8;

// RNE fp32->bf16 (no NaN path: inputs are finite randn products)
static __device__ __forceinline__ unsigned short f2bf_rne(float x) {
    unsigned u = __builtin_bit_cast(unsigned, x);
    u += 0x7fffu + ((u >> 16) & 1u);
    return (unsigned short)(u >> 16);
}
// pack two fp32 -> bf16x2 in one u32 (compiler folds the merge to v_perm)
static __device__ __forceinline__ unsigned pack2_bf16(float a, float b) {
    unsigned ua = __builtin_bit_cast(unsigned, a);
    unsigned ub = __builtin_bit_cast(unsigned, b);
    ua += 0x7fffu + ((ua >> 16) & 1u);
    ub += 0x7fffu + ((ub >> 16) & 1u);
    return (ua >> 16) | (ub & 0xffff0000u);
}

static __device__ __forceinline__ float dot8(const float4 a0, const float4 a1,
                                             const float4 x0, const float4 x1v) {
    return a0.x * x0.x + a0.y * x0.y + a0.z * x0.z + a0.w * x0.w
         + a1.x * x1v.x + a1.y * x1v.y + a1.z * x1v.z + a1.w * x1v.w;
}

// ---------------------------------------------------------------------------
// Kernel 1 (unchanged from 152.6us best): one wave per reduction row.
// rows [0, F*D):      M[fragidx(f,d)] = V[f][d] + dot(W[f][d][:], x2)  (bf16, frag order)
// rows [F*D, F*D+F):  c[f] = b[f] + dot(V[f][512:], x2)                (fp32)
// 8208 blocks x 256 thr -> 32 waves/CU, streaming-bound.
// ---------------------------------------------------------------------------
__global__ __launch_bounds__(256) void prep_kernel(
    const float* __restrict__ x2,
    const float* __restrict__ V,
    const float* __restrict__ W,
    const float* __restrict__ b,
    unsigned short* __restrict__ Mout,
    float* __restrict__ cout)
{
    int wave = (blockIdx.x * 256 + threadIdx.x) >> 6;
    int lane = threadIdx.x & 63;

    const float4* src;
    if (wave < FDIM * DDIM) {
        src = (const float4*)(W + (size_t)wave * DDIM);
    } else {
        int f = wave - FDIM * DDIM;
        src = (const float4*)(V + (size_t)f * (2 * DDIM) + DDIM);
    }
    const float4* xx = (const float4*)x2;

    float4 a0 = src[lane];
    float4 a1 = src[lane + 64];
    float4 x0 = xx[lane];
    float4 x1v = xx[lane + 64];

    float s = dot8(a0, a1, x0, x1v);

    #pragma unroll
    for (int m = 32; m >= 1; m >>= 1) s += __shfl_xor(s, m);

    if (lane == 0) {
        if (wave < FDIM * DDIM) {
            int f = wave >> 9, d = wave & 511;
            float mval = s + V[(size_t)f * (2 * DDIM) + d];
            // MFMA B-frag order so main's loads are linear/coalesced:
            // frag u4-index = (ks*4 + t)*64 + lane, lane = sub*16 + fl
            int t  = f >> 4, fl = f & 15;
            int ks = d >> 5, sub = (d >> 3) & 3, j = d & 7;
            int fragidx = (((ks * 4 + t) * 64 + sub * 16 + fl) << 3) + j;
            Mout[fragidx] = f2bf_rne(mval);
        } else {
            int f = wave - FDIM * DDIM;
            cout[f] = s + b[f];
        }
    }
}

// ---------------------------------------------------------------------------
// Kernel 2 v2: K-split across wave pairs, M read directly from global (L2).
//   - 1024 blocks x 256 thr, 32 rows/block (2 row-tiles x 2 K-halves).
//   - wave w: tile = w>>1 (16 rows), khalf = w&1 (K=256 slice).
//   - No 64KB LDS M-stage -> not LDS-capped; 4096 waves = 16 waves/CU.
//   - Partial accs combined via 8KB LDS; khalf==0 waves run the epilogue.
// ---------------------------------------------------------------------------
__global__ __launch_bounds__(256) void main_kernel(
    const float* __restrict__ x1,
    const unsigned short* __restrict__ Mg,   // bf16, frag order (4096 x uint4)
    const float* __restrict__ cg_,           // [64]
    const float* __restrict__ U,             // [64]
    float* __restrict__ out)                 // [32768]
{
    __shared__ f32x4 red[2][64][4];   // 8 KB partial-acc exchange

    int tid   = threadIdx.x;
    int wave  = tid >> 6;
    int lane  = tid & 63;
    int tile  = wave >> 1;    // 0..1
    int khalf = wave & 1;     // 0..1

    int q  = lane >> 4;       // quad
    int fl = lane & 15;

    int row0 = blockIdx.x * 32 + tile * 16;
    const float* arow = x1 + (size_t)(row0 + fl) * DDIM + q * 8 + khalf * 256;

    const bf16x8* Mf = (const bf16x8*)Mg;

    f32x4 acc0 = {0.f,0.f,0.f,0.f}, acc1 = {0.f,0.f,0.f,0.f};
    f32x4 acc2 = {0.f,0.f,0.f,0.f}, acc3 = {0.f,0.f,0.f,0.f};

    #pragma unroll 4
    for (int ks = 0; ks < 8; ++ks) {
        int ksg = khalf * 8 + ks;
        float4 av0 = *(const float4*)(arow + ks * 32);
        float4 av1 = *(const float4*)(arow + ks * 32 + 4);

        union { bf16x8 v; unsigned u32[4]; } af;
        af.u32[0] = pack2_bf16(av0.x, av0.y);
        af.u32[1] = pack2_bf16(av0.z, av0.w);
        af.u32[2] = pack2_bf16(av1.x, av1.y);
        af.u32[3] = pack2_bf16(av1.z, av1.w);

        bf16x8 b0 = Mf[(ksg * 4 + 0) * 64 + lane];
        bf16x8 b1 = Mf[(ksg * 4 + 1) * 64 + lane];
        bf16x8 b2 = Mf[(ksg * 4 + 2) * 64 + lane];
        bf16x8 b3 = Mf[(ksg * 4 + 3) * 64 + lane];

        acc0 = __builtin_amdgcn_mfma_f32_16x16x32_bf16(af.v, b0, acc0, 0, 0, 0);
        acc1 = __builtin_amdgcn_mfma_f32_16x16x32_bf16(af.v, b1, acc1, 0, 0, 0);
        acc2 = __builtin_amdgcn_mfma_f32_16x16x32_bf16(af.v, b2, acc2, 0, 0, 0);
        acc3 = __builtin_amdgcn_mfma_f32_16x16x32_bf16(af.v, b3, acc3, 0, 0, 0);
    }

    // Combine K-halves through LDS.
    if (khalf == 1) {
        red[tile][lane][0] = acc0;
        red[tile][lane][1] = acc1;
        red[tile][lane][2] = acc2;
        red[tile][lane][3] = acc3;
    }
    __syncthreads();
    if (khalf == 1) return;

    acc0 += red[tile][lane][0];
    acc1 += red[tile][lane][1];
    acc2 += red[tile][lane][2];
    acc3 += red[tile][lane][3];

    // Epilogue. C/D layout: col(f_local)=lane&15, row=q*4+reg.
    float cf0 = cg_[fl], cf1 = cg_[16 + fl], cf2 = cg_[32 + fl], cf3 = cg_[48 + fl];
    float uf0 = U[fl],   uf1 = U[16 + fl],  uf2 = U[32 + fl],  uf3 = U[48 + fl];

    #pragma unroll
    for (int r = 0; r < 4; ++r) {
        float f0 = acc0[r] + cf0;
        float f1 = acc1[r] + cf1;
        float f2 = acc2[r] + cf2;
        float f3 = acc3[r] + cf3;

        float s = fabsf(f0) + fabsf(f1) + fabsf(f2) + fabsf(f3);
        s += __shfl_xor(s, 1); s += __shfl_xor(s, 2);
        s += __shfl_xor(s, 4); s += __shfl_xor(s, 8);
        float denom = fmaxf(s, 1e-12f);

        float o = fmaxf(f0, 0.f) * uf0 + fmaxf(f1, 0.f) * uf1
                + fmaxf(f2, 0.f) * uf2 + fmaxf(f3, 0.f) * uf3;
        o += __shfl_xor(o, 1); o += __shfl_xor(o, 2);
        o += __shfl_xor(o, 4); o += __shfl_xor(o, 8);

        if (fl == 0) {
            out[row0 + q * 4 + r] = o / denom;
        }
    }
}

extern "C" void kernel_launch(void* const* d_in, const int* in_sizes, int n_in,
                              void* d_out, int out_size, void* d_ws, size_t ws_size,
                              hipStream_t stream) {
    const float* x1 = (const float*)d_in[0];
    const float* x2 = (const float*)d_in[1];
    const float* V  = (const float*)d_in[2];
    const float* W  = (const float*)d_in[3];
    const float* b  = (const float*)d_in[4];
    const float* U  = (const float*)d_in[5];
    float* outp = (float*)d_out;

    unsigned short* M = (unsigned short*)d_ws;                   // 64*512 bf16 = 64 KB (frag order)
    float* c          = (float*)((char*)d_ws + FDIM * DDIM * 2); // 64 fp32

    // rows = F*D (M) + F (c) = 32832; 4 waves/block -> 8208 blocks
    prep_kernel<<<8208, 256, 0, stream>>>(x2, V, W, b, M, c);
    // 32768 rows / 32 per block = 1024 blocks
    main_kernel<<<1024, 256, 0, stream>>>(x1, M, c, U, outp);
}